// Round 5
// baseline (760.237 us; speedup 1.0000x reference)
//
#include <hip/hip_runtime.h>

#define HH 320
#define WW 320
#define BB 8
static constexpr float EPS = 1e-5f;

typedef __attribute__((ext_vector_type(8))) short bf16x8;
typedef __attribute__((ext_vector_type(4))) float f32x4;

__device__ inline float bf2f(unsigned short u) {
    union { unsigned int i; float f; } v; v.i = ((unsigned int)u) << 16; return v.f;
}
__device__ inline unsigned short f2bf(float f) {
    union { float f; unsigned int i; } v; v.f = f;
    unsigned int r = v.i + 0x7fffu + ((v.i >> 16) & 1u);
    return (unsigned short)(r >> 16);
}
__device__ inline void glds16(const void* g, void* l) {
    __builtin_amdgcn_global_load_lds(
        (const __attribute__((address_space(1))) unsigned int*)g,
        (__attribute__((address_space(3))) unsigned int*)l, 16, 0, 0);
}

// ---------------- NCHW fp32 -> NHWC bf16 (CIN=32) ----------------
__global__ __launch_bounds__(256) void prep_hwc(const float* __restrict__ in,
                                                unsigned short* __restrict__ out)
{
    __shared__ float sT[32][65];
    const int tid = threadIdx.x;
    const int x0  = blockIdx.x * 64;
    const int y   = blockIdx.y;
    const int b   = blockIdx.z;
    for (int e = tid; e < 32 * 64; e += 256) {
        int c = e >> 6, x = e & 63;
        sT[c][x] = in[(((size_t)(b * 32 + c) * HH) + y) * WW + x0 + x];
    }
    __syncthreads();
    for (int e = tid; e < 64 * 32; e += 256) {
        int x = e >> 5, c = e & 31;
        out[((((size_t)b * HH + y) * WW) + x0 + x) * 32 + c] = f2bf(sT[c][x]);
    }
}

// ---------------- weights OIHW fp32 -> [kk][oc][ic] bf16 ----------------
__global__ void wprep_kernel(const float* __restrict__ w1, const float* __restrict__ w2,
                             unsigned short* __restrict__ wt1, unsigned short* __restrict__ wt2)
{
    int i = blockIdx.x * 256 + threadIdx.x;
    if (i < 9 * 64 * 32) {
        int ic = i & 31, oc = (i >> 5) & 63, kk = i >> 11;
        wt1[i] = f2bf(w1[(oc * 32 + ic) * 9 + kk]);
    }
    if (i < 9 * 64 * 64) {
        int ic = i & 63, oc = (i >> 6) & 63, kk = i >> 12;
        wt2[i] = f2bf(w2[(oc * 64 + ic) * 9 + kk]);
    }
}

// ---------------- implicit-GEMM conv 3x3 via MFMA, pipelined ----------------
// Block: 4 waves, wave w owns output row (tile_y0 + w). Tile: 4 rows x 64 px x 64 oc.
// Each block runs 4 consecutive y-subtiles => NS = 4*ICC pipeline steps with
// double-buffered sA: issue stage(s+1) -> compute(s) -> [epilogue] -> barrier.
// NORM=0: stage via global_load_lds (pure copy, pre-swizzled source).
// NORM=1: reg-stage with fused relu((v-mean)*rstd) (T14 issue-early/write-late).
// ORIENT 1: D[oc][px], bf16 NHWC out (conv1).  ORIENT 0: D[px][oc], fp32 NCHW out (conv2).
template<int CIN, int ORIENT, int NORM>
__global__ __launch_bounds__(256, 3) void conv_mfma(
    const unsigned short* __restrict__ in_hwc,   // [B][H][W][CIN] bf16
    const float2* __restrict__ stats_in,         // [B*CIN] (NORM)
    const unsigned short* __restrict__ wt,       // [9][64][CIN] bf16
    const float* __restrict__ bias,              // [64]
    unsigned short* __restrict__ out_hwc,        // ORIENT 1
    float* __restrict__ out_nchw,                // ORIENT 0
    float2* __restrict__ partials)               // [B*400][64]
{
    constexpr int ICC = CIN / 32;
    constexpr int NS  = 4 * ICC;

    __shared__ __align__(16) unsigned short sA[2][6 * 264 * 8];   // 2 x 25344 B
    __shared__ float sRedS[256];
    __shared__ float sRedSS[256];
    __shared__ float2 sStats[64];

    const int tid = threadIdx.x;
    const int x0  = blockIdx.x * 64;
    const int yb  = blockIdx.y * 16;
    const int b   = blockIdx.z;
    const int w   = tid >> 6;
    const int l   = tid & 63;
    const int lm  = l & 15;
    const int g   = l >> 4;

    if (NORM) {
        if (tid < 64) sStats[tid] = stats_in[b * 64 + tid];
        __syncthreads();
    }

    bf16x8 ld[7];

    auto stage_issue = [&](int s) {
        const int t = s / ICC, icc = s % ICC;
        const int y0 = yb + t * 4;
        unsigned short* buf = sA[s & 1];
        if (NORM == 0) {
#pragma unroll
            for (int r = 0; r < 6; ++r) {
                if ((r & 3) != w) continue;
                int gy = y0 + r - 1;
                unsigned short* ldsrow = buf + r * 2112;
                if ((unsigned)gy < HH) {
                    const unsigned short* rowbase =
                        in_hwc + ((size_t)(b * HH + gy) * WW) * CIN + icc * 32;
#pragma unroll
                    for (int i = 0; i < 4; ++i) {
                        int u  = 4 + i * 64 + l;
                        int x  = u >> 2;
                        int cs = (u & 3) ^ ((x >> 1) & 3);
                        glds16(rowbase + (size_t)(x0 + x - 1) * CIN + cs * 8,
                               ldsrow + (size_t)(4 + i * 64) * 8);
                    }
                } else {
                    for (int u = l; u < 264; u += 64)
                        *(bf16x8*)(ldsrow + u * 8) = (bf16x8){0,0,0,0,0,0,0,0};
                }
            }
            // edge px slots 0 and 65 (swizzle is identity at these x)
            if (tid < 48) {
                int icq = tid & 3, side = (tid >> 2) & 1, r = tid >> 3;
                int xs = side ? 65 : 0;
                int gy = y0 + r - 1, gx = x0 + xs - 1;
                bf16x8 v = (bf16x8){0,0,0,0,0,0,0,0};
                if ((unsigned)gy < HH && (unsigned)gx < WW)
                    v = *(const bf16x8*)&in_hwc[(((size_t)(b * HH + gy) * WW) + gx) * CIN + icc * 32 + icq * 8];
                *(bf16x8*)(buf + r * 2112 + (xs * 4 + icq) * 8) = v;
            }
        } else {
#pragma unroll
            for (int k = 0; k < 7; ++k) {
                int e = tid + k * 256;
                if (e < 1584) {
                    int r = e / 264, rem = e % 264;
                    int x = rem >> 2, icq = rem & 3;
                    int cs = icq ^ ((x >> 1) & 3);
                    int gy = y0 + r - 1, gx = x0 + x - 1;
                    bf16x8 v = (bf16x8){0,0,0,0,0,0,0,0};
                    if ((unsigned)gy < HH && (unsigned)gx < WW)
                        v = *(const bf16x8*)&in_hwc[(((size_t)(b * HH + gy) * WW) + gx) * CIN + icc * 32 + cs * 8];
                    ld[k] = v;
                }
            }
        }
    };

    auto stage_finish = [&](int s) {
        if (NORM == 0) return;
        const int icc = s % ICC;
        unsigned short* buf = sA[s & 1];
#pragma unroll
        for (int k = 0; k < 7; ++k) {
            int e = tid + k * 256;
            if (e < 1584) {
                int r = e / 264, rem = e % 264;
                int x = rem >> 2, icq = rem & 3;
                int cs = icq ^ ((x >> 1) & 3);
                unsigned short res[8];
#pragma unroll
                for (int j = 0; j < 8; ++j) {
                    float2 ms = sStats[icc * 32 + cs * 8 + j];
                    res[j] = f2bf(fmaxf((bf2f(((unsigned short*)&ld[k])[j]) - ms.x) * ms.y, 0.f));
                }
                *(bf16x8*)(buf + r * 2112 + (x * 4 + icq) * 8) = *(bf16x8*)res;
            }
        }
    };

    f32x4 acc[4][4];
#pragma unroll
    for (int fx = 0; fx < 4; ++fx)
#pragma unroll
        for (int fn = 0; fn < 4; ++fn)
            acc[fx][fn] = (f32x4){0.f, 0.f, 0.f, 0.f};

    auto compute = [&](int s) {
        const int icc = s % ICC;
        const unsigned short* buf = sA[s & 1];
        const unsigned short* wbase = wt + icc * 32;
#pragma unroll
        for (int kk = 0; kk < 9; ++kk) {
            const int ky = kk / 3, kx = kk - ky * 3;
            bf16x8 af[4], bfr[4];
#pragma unroll
            for (int fx = 0; fx < 4; ++fx) {
                int xl = fx * 16 + lm + kx;
                int u  = (xl * 4 + g) ^ ((xl >> 1) & 3);
                af[fx] = *(const bf16x8*)(buf + (w + ky) * 2112 + u * 8);
            }
#pragma unroll
            for (int fn = 0; fn < 4; ++fn)
                bfr[fn] = *(const bf16x8*)&wbase[(size_t)(kk * 64 + fn * 16 + lm) * CIN + g * 8];
#pragma unroll
            for (int fn = 0; fn < 4; ++fn)
#pragma unroll
                for (int fx = 0; fx < 4; ++fx)
                    acc[fx][fn] = ORIENT
                        ? __builtin_amdgcn_mfma_f32_16x16x32_bf16(bfr[fn], af[fx], acc[fx][fn], 0, 0, 0)
                        : __builtin_amdgcn_mfma_f32_16x16x32_bf16(af[fx], bfr[fn], acc[fx][fn], 0, 0, 0);
        }
    };

    auto epilogue = [&](int t) {
        const int row = yb + t * 4 + w;
        if (ORIENT == 1) {
            // lane: oc = 16fo + 4g + j, px = x0 + 16fp + lm
#pragma unroll
            for (int fo = 0; fo < 4; ++fo) {
                float4 b4 = *(const float4*)&bias[fo * 16 + g * 4];
                float bb[4] = {b4.x, b4.y, b4.z, b4.w};
                float sj[4] = {0,0,0,0}, qj[4] = {0,0,0,0};
#pragma unroll
                for (int fp = 0; fp < 4; ++fp) {
                    unsigned short pk[4];
#pragma unroll
                    for (int j = 0; j < 4; ++j) {
                        float v = acc[fp][fo][j] + bb[j];
                        sj[j] += v; qj[j] += v * v;
                        pk[j] = f2bf(v);
                    }
                    *(short4*)&out_hwc[(((size_t)b * HH + row) * WW + x0 + fp * 16 + lm) * 64 + fo * 16 + g * 4] =
                        *(short4*)pk;
                }
#pragma unroll
                for (int m = 1; m <= 8; m <<= 1)
#pragma unroll
                    for (int j = 0; j < 4; ++j) {
                        sj[j] += __shfl_xor(sj[j], m);
                        qj[j] += __shfl_xor(qj[j], m);
                    }
                if (lm == 0) {
#pragma unroll
                    for (int j = 0; j < 4; ++j) {
                        sRedS [w * 64 + fo * 16 + g * 4 + j] = sj[j];
                        sRedSS[w * 64 + fo * 16 + g * 4 + j] = qj[j];
                    }
                }
            }
        } else {
            // lane: oc = 16fn + lm, px = x0 + 16fx + 4g + j
#pragma unroll
            for (int fn = 0; fn < 4; ++fn) {
                float bv = bias[fn * 16 + lm];
                float s = 0.f, ss = 0.f;
#pragma unroll
                for (int fx = 0; fx < 4; ++fx) {
                    float v0 = acc[fx][fn][0] + bv, v1 = acc[fx][fn][1] + bv;
                    float v2 = acc[fx][fn][2] + bv, v3 = acc[fx][fn][3] + bv;
                    s += v0 + v1 + v2 + v3;
                    ss += v0 * v0 + v1 * v1 + v2 * v2 + v3 * v3;
                    *(float4*)&out_nchw[(((size_t)(b * 64 + fn * 16 + lm) * HH) + row) * WW + x0 + fx * 16 + g * 4]
                        = make_float4(v0, v1, v2, v3);
                }
                s  += __shfl_xor(s, 16);  s  += __shfl_xor(s, 32);
                ss += __shfl_xor(ss, 16); ss += __shfl_xor(ss, 32);
                if (l < 16) { sRedS[w * 64 + fn * 16 + l] = s; sRedSS[w * 64 + fn * 16 + l] = ss; }
            }
        }
        __syncthreads();
        if (tid < 64) {
            float S = 0.f, SS = 0.f;
#pragma unroll
            for (int q = 0; q < 4; ++q) { S += sRedS[q * 64 + tid]; SS += sRedSS[q * 64 + tid]; }
            int tile = (blockIdx.y * 4 + t) * 5 + blockIdx.x;
            partials[((size_t)b * 400 + tile) * 64 + tid] = make_float2(S, SS);
        }
#pragma unroll
        for (int fx = 0; fx < 4; ++fx)
#pragma unroll
            for (int fn = 0; fn < 4; ++fn)
                acc[fx][fn] = (f32x4){0.f, 0.f, 0.f, 0.f};
    };

    // -------- pipeline --------
    stage_issue(0);
    stage_finish(0);
    __syncthreads();
    for (int s = 0; s < NS; ++s) {
        if (s + 1 < NS) stage_issue(s + 1);
        compute(s);
        if (s % ICC == ICC - 1) epilogue(s / ICC);
        if (s + 1 < NS) stage_finish(s + 1);
        __syncthreads();
    }
}

// ---------------- partials -> (mean, rstd) ----------------
__global__ __launch_bounds__(256) void reduce_stats(const float2* __restrict__ partials,
                                                    float2* __restrict__ stats)
{
    const int b  = blockIdx.x;
    const int oc = threadIdx.x & 63;
    const int q  = threadIdx.x >> 6;
    float s = 0.f, ss = 0.f;
    for (int i = q; i < 400; i += 4) {
        float2 p = partials[((size_t)b * 400 + i) * 64 + oc];
        s += p.x; ss += p.y;
    }
    __shared__ float2 red[4][64];
    red[q][oc] = make_float2(s, ss);
    __syncthreads();
    if (threadIdx.x < 64) {
        float S = 0.f, SS = 0.f;
#pragma unroll
        for (int k = 0; k < 4; ++k) { S += red[k][threadIdx.x].x; SS += red[k][threadIdx.x].y; }
        const float n = (float)(HH * WW);
        float mean = S / n;
        float var  = fmaxf(SS / n - mean * mean, 0.f);
        stats[b * 64 + threadIdx.x] = make_float2(mean, rsqrtf(var + EPS));
    }
}

// ---------------- in-place normalize + relu on NCHW fp32 ----------------
__global__ __launch_bounds__(256) void finalize_kernel(float* __restrict__ out,
                                                       const float2* __restrict__ stats)
{
    const int bc  = blockIdx.x >> 2;
    const int seg = blockIdx.x & 3;
    float2 ms = stats[bc];
    float4* p = (float4*)(out + (size_t)bc * (HH * WW));
    const int n4 = HH * WW / 4;
    for (int i = seg * (n4 / 4) + threadIdx.x; i < (seg + 1) * (n4 / 4); i += 256) {
        float4 v = p[i];
        v.x = fmaxf((v.x - ms.x) * ms.y, 0.f);
        v.y = fmaxf((v.y - ms.x) * ms.y, 0.f);
        v.z = fmaxf((v.z - ms.x) * ms.y, 0.f);
        v.w = fmaxf((v.w - ms.x) * ms.y, 0.f);
        p[i] = v;
    }
}

extern "C" void kernel_launch(void* const* d_in, const int* in_sizes, int n_in,
                              void* d_out, int out_size, void* d_ws, size_t ws_size,
                              hipStream_t stream)
{
    const float* x  = (const float*)d_in[0];
    const float* w1 = (const float*)d_in[1];
    const float* b1 = (const float*)d_in[2];
    const float* w2 = (const float*)d_in[3];
    const float* b2 = (const float*)d_in[4];
    float* out = (float*)d_out;

    char* ws = (char*)d_ws;
    size_t off = 0;
    unsigned short* h_hwc = (unsigned short*)(ws + off); off += (size_t)BB * HH * WW * 64 * 2;
    unsigned short* x_hwc = (unsigned short*)(ws + off); off += (size_t)BB * HH * WW * 32 * 2;
    unsigned short* wt1   = (unsigned short*)(ws + off); off += 9 * 64 * 32 * 2;
    unsigned short* wt2   = (unsigned short*)(ws + off); off += 9 * 64 * 64 * 2;
    float2* partials      = (float2*)(ws + off);         off += (size_t)BB * 400 * 64 * sizeof(float2);
    float2* stats1        = (float2*)(ws + off);         off += 512 * sizeof(float2);
    float2* stats2        = (float2*)(ws + off);         off += 512 * sizeof(float2);

    dim3 cgrid(5, 20, BB);   // x-tiles, y-supertiles (4 sub-tiles each), batch

    prep_hwc<<<dim3(5, HH, BB), 256, 0, stream>>>(x, x_hwc);
    wprep_kernel<<<144, 256, 0, stream>>>(w1, w2, wt1, wt2);

    // conv1: raw conv -> NHWC bf16 h + stats partials
    conv_mfma<32, 1, 0><<<cgrid, 256, 0, stream>>>(x_hwc, nullptr, wt1, b1,
                                                   h_hwc, nullptr, partials);
    reduce_stats<<<BB, 256, 0, stream>>>(partials, stats1);
    // conv2: fused norm(stats1)+relu on load -> raw conv NCHW fp32 out + partials
    conv_mfma<64, 0, 1><<<cgrid, 256, 0, stream>>>(h_hwc, stats1, wt2, b2,
                                                   nullptr, out, partials);
    reduce_stats<<<BB, 256, 0, stream>>>(partials, stats2);
    // in-place normalize + relu on d_out
    finalize_kernel<<<BB * 64 * 4, 256, 0, stream>>>(out, stats2);
}

// Round 6
// 479.844 us; speedup vs baseline: 1.5843x; 1.5843x over previous
//
#include <hip/hip_runtime.h>

#define HH 320
#define WW 320
#define BB 8
static constexpr float EPS = 1e-5f;

typedef __attribute__((ext_vector_type(8))) short bf16x8;
typedef __attribute__((ext_vector_type(4))) float f32x4;

__device__ inline float bf2f(unsigned short u) {
    union { unsigned int i; float f; } v; v.i = ((unsigned int)u) << 16; return v.f;
}
__device__ inline unsigned short f2bf(float f) {
    union { float f; unsigned int i; } v; v.f = f;
    unsigned int r = v.i + 0x7fffu + ((v.i >> 16) & 1u);
    return (unsigned short)(r >> 16);
}
__device__ inline void glds16(const void* g, void* l) {
    __builtin_amdgcn_global_load_lds(
        (const __attribute__((address_space(1))) unsigned int*)g,
        (__attribute__((address_space(3))) unsigned int*)l, 16, 0, 0);
}

// ---------------- NCHW fp32 -> NHWC bf16 (CIN=32) ----------------
__global__ __launch_bounds__(256) void prep_hwc(const float* __restrict__ in,
                                                unsigned short* __restrict__ out)
{
    __shared__ float sT[32][65];
    const int tid = threadIdx.x;
    const int x0  = blockIdx.x * 64;
    const int y   = blockIdx.y;
    const int b   = blockIdx.z;
    for (int e = tid; e < 32 * 64; e += 256) {
        int c = e >> 6, x = e & 63;
        sT[c][x] = in[(((size_t)(b * 32 + c) * HH) + y) * WW + x0 + x];
    }
    __syncthreads();
    for (int e = tid; e < 64 * 32; e += 256) {
        int x = e >> 5, c = e & 31;
        out[((((size_t)b * HH + y) * WW) + x0 + x) * 32 + c] = f2bf(sT[c][x]);
    }
}

// ---------------- weights OIHW fp32 -> [kk][oc][ic] bf16 ----------------
__global__ void wprep_kernel(const float* __restrict__ w1, const float* __restrict__ w2,
                             unsigned short* __restrict__ wt1, unsigned short* __restrict__ wt2)
{
    int i = blockIdx.x * 256 + threadIdx.x;
    if (i < 9 * 64 * 32) {
        int ic = i & 31, oc = (i >> 5) & 63, kk = i >> 11;
        wt1[i] = f2bf(w1[(oc * 32 + ic) * 9 + kk]);
    }
    if (i < 9 * 64 * 64) {
        int ic = i & 63, oc = (i >> 6) & 63, kk = i >> 12;
        wt2[i] = f2bf(w2[(oc * 64 + ic) * 9 + kk]);
    }
}

// ---------------- implicit-GEMM conv 3x3 via MFMA ----------------
// Block: 4 waves, wave w owns output row y0+w. Tile: 4 rows x 64 px x 64 oc.
// acc[4][4] (64 acc regs) -> target 3 blocks/CU (12 waves/CU).
// A staged via global_load_lds into bank-swizzled linear LDS (swizzle applied by
// permuting the per-lane global source). B (weights) read per-fragment from L1/L2.
// CIN=64: K double-buffer (stage ch1 overlaps compute ch0).
// ORIENT 1: D[oc][px], bf16x4 NHWC stores (conv1).
// ORIENT 0: D[px][oc], float4 NCHW stores (conv2).
template<int CIN, int ORIENT>
__global__ __launch_bounds__(256, 3) void conv_mfma(
    const unsigned short* __restrict__ in_hwc,   // [B][H][W][CIN] bf16
    const unsigned short* __restrict__ wt,       // [9][64][CIN] bf16
    const float* __restrict__ bias,              // [64]
    unsigned short* __restrict__ out_hwc,        // ORIENT 1
    float* __restrict__ out_nchw,                // ORIENT 0
    float2* __restrict__ partials)               // [B*400][64]
{
    constexpr int ICC  = CIN / 32;
    constexpr int NBUF = (ICC > 1) ? 2 : 1;

    __shared__ __align__(16) unsigned short sA[NBUF][6 * 264 * 8];  // 25344 B per buf
    __shared__ float sRedS[256];
    __shared__ float sRedSS[256];

    const int tid = threadIdx.x;
    const int x0  = blockIdx.x * 64;
    const int y0  = blockIdx.y * 4;
    const int b   = blockIdx.z;
    const int w   = tid >> 6;
    const int l   = tid & 63;
    const int lm  = l & 15;
    const int g   = l >> 4;

    f32x4 acc[4][4];
#pragma unroll
    for (int fx = 0; fx < 4; ++fx)
#pragma unroll
        for (int fn = 0; fn < 4; ++fn)
            acc[fx][fn] = (f32x4){0.f, 0.f, 0.f, 0.f};

    auto stage = [&](int icc, unsigned short* buf) {
        for (int r = w; r < 6; r += 4) {
            int gy = y0 + r - 1;
            unsigned short* ldsrow = buf + r * 2112;
            if ((unsigned)gy < HH) {
                const unsigned short* rowbase =
                    in_hwc + ((size_t)(b * HH + gy) * WW) * CIN + icc * 32;
#pragma unroll
                for (int i = 0; i < 4; ++i) {
                    int u  = 4 + i * 64 + l;           // dest 16B unit
                    int x  = u >> 2;                   // px slot 1..64
                    int cs = (u & 3) ^ ((x >> 1) & 3); // inverse swizzle on source
                    glds16(rowbase + (size_t)(x0 + x - 1) * CIN + cs * 8,
                           ldsrow + (size_t)(4 + i * 64) * 8);
                }
            } else {
                for (int u2 = l; u2 < 264; u2 += 64)
                    *(bf16x8*)(ldsrow + u2 * 8) = (bf16x8){0,0,0,0,0,0,0,0};
            }
        }
        // edge px slots 0 and 65 (swizzle is identity at these x)
        if (tid < 48) {
            int icq = tid & 3, side = (tid >> 2) & 1, r = tid >> 3;
            int xs = side ? 65 : 0;
            int gy = y0 + r - 1, gx = x0 + xs - 1;
            bf16x8 v = (bf16x8){0,0,0,0,0,0,0,0};
            if ((unsigned)gy < HH && (unsigned)gx < WW)
                v = *(const bf16x8*)&in_hwc[(((size_t)(b * HH + gy) * WW) + gx) * CIN + icc * 32 + icq * 8];
            *(bf16x8*)(buf + r * 2112 + (xs * 4 + icq) * 8) = v;
        }
    };

    auto compute = [&](int icc, const unsigned short* buf) {
        const unsigned short* wbase = wt + icc * 32;
#pragma unroll
        for (int kk = 0; kk < 9; ++kk) {
            const int ky = kk / 3, kx = kk - ky * 3;
            bf16x8 af[4], bfr[4];
#pragma unroll
            for (int fx = 0; fx < 4; ++fx) {
                int xl = fx * 16 + lm + kx;
                int u  = (xl * 4 + g) ^ ((xl >> 1) & 3);
                af[fx] = *(const bf16x8*)(buf + (w + ky) * 2112 + u * 8);
            }
#pragma unroll
            for (int fn = 0; fn < 4; ++fn)
                bfr[fn] = *(const bf16x8*)&wbase[(size_t)(kk * 64 + fn * 16 + lm) * CIN + g * 8];
#pragma unroll
            for (int fn = 0; fn < 4; ++fn)
#pragma unroll
                for (int fx = 0; fx < 4; ++fx)
                    acc[fx][fn] = ORIENT
                        ? __builtin_amdgcn_mfma_f32_16x16x32_bf16(bfr[fn], af[fx], acc[fx][fn], 0, 0, 0)
                        : __builtin_amdgcn_mfma_f32_16x16x32_bf16(af[fx], bfr[fn], acc[fx][fn], 0, 0, 0);
        }
    };

    stage(0, sA[0]);
    __syncthreads();
    if constexpr (ICC == 2) {
        stage(1, sA[1]);          // glds issue overlaps compute(0)
        compute(0, sA[0]);
        __syncthreads();          // drains vmcnt -> chunk 1 ready
        compute(1, sA[1]);
    } else {
        compute(0, sA[0]);
    }

    const int row = y0 + w;
    if (ORIENT == 1) {
        // lane: oc = 16*fo + 4g + j, px = x0 + 16*fp + lm
#pragma unroll
        for (int fo = 0; fo < 4; ++fo) {
            float4 b4 = *(const float4*)&bias[fo * 16 + g * 4];
            float bb[4] = {b4.x, b4.y, b4.z, b4.w};
            float sj[4] = {0,0,0,0}, qj[4] = {0,0,0,0};
#pragma unroll
            for (int fp = 0; fp < 4; ++fp) {
                unsigned short pk[4];
#pragma unroll
                for (int j = 0; j < 4; ++j) {
                    float v = acc[fp][fo][j] + bb[j];
                    sj[j] += v; qj[j] += v * v;
                    pk[j] = f2bf(v);
                }
                *(short4*)&out_hwc[(((size_t)b * HH + row) * WW + x0 + fp * 16 + lm) * 64 + fo * 16 + g * 4] =
                    *(short4*)pk;
            }
#pragma unroll
            for (int m = 1; m <= 8; m <<= 1)
#pragma unroll
                for (int j = 0; j < 4; ++j) {
                    sj[j] += __shfl_xor(sj[j], m);
                    qj[j] += __shfl_xor(qj[j], m);
                }
            if (lm == 0) {
#pragma unroll
                for (int j = 0; j < 4; ++j) {
                    sRedS [w * 64 + fo * 16 + g * 4 + j] = sj[j];
                    sRedSS[w * 64 + fo * 16 + g * 4 + j] = qj[j];
                }
            }
        }
    } else {
        // lane: oc = 16*fn + lm, px = x0 + 16*fx + 4g + j
#pragma unroll
        for (int fn = 0; fn < 4; ++fn) {
            float bv = bias[fn * 16 + lm];
            float s = 0.f, ss = 0.f;
#pragma unroll
            for (int fx = 0; fx < 4; ++fx) {
                float v0 = acc[fx][fn][0] + bv, v1 = acc[fx][fn][1] + bv;
                float v2 = acc[fx][fn][2] + bv, v3 = acc[fx][fn][3] + bv;
                s  += v0 + v1 + v2 + v3;
                ss += v0 * v0 + v1 * v1 + v2 * v2 + v3 * v3;
                *(float4*)&out_nchw[(((size_t)(b * 64 + fn * 16 + lm) * HH) + row) * WW + x0 + fx * 16 + g * 4]
                    = make_float4(v0, v1, v2, v3);
            }
            s  += __shfl_xor(s, 16);  s  += __shfl_xor(s, 32);
            ss += __shfl_xor(ss, 16); ss += __shfl_xor(ss, 32);
            if (l < 16) { sRedS[w * 64 + fn * 16 + l] = s; sRedSS[w * 64 + fn * 16 + l] = ss; }
        }
    }

    __syncthreads();
    if (tid < 64) {
        float S = 0.f, SS = 0.f;
#pragma unroll
        for (int q = 0; q < 4; ++q) { S += sRedS[q * 64 + tid]; SS += sRedSS[q * 64 + tid]; }
        partials[((size_t)b * 400 + blockIdx.y * 5 + blockIdx.x) * 64 + tid] = make_float2(S, SS);
    }
}

// ---------------- partials -> (mean, rstd) ----------------
__global__ __launch_bounds__(256) void reduce_stats(const float2* __restrict__ partials,
                                                    float2* __restrict__ stats)
{
    const int b  = blockIdx.x;
    const int oc = threadIdx.x & 63;
    const int q  = threadIdx.x >> 6;
    float s = 0.f, ss = 0.f;
    for (int i = q; i < 400; i += 4) {
        float2 p = partials[((size_t)b * 400 + i) * 64 + oc];
        s += p.x; ss += p.y;
    }
    __shared__ float2 red[4][64];
    red[q][oc] = make_float2(s, ss);
    __syncthreads();
    if (threadIdx.x < 64) {
        float S = 0.f, SS = 0.f;
#pragma unroll
        for (int k = 0; k < 4; ++k) { S += red[k][threadIdx.x].x; SS += red[k][threadIdx.x].y; }
        const float n = (float)(HH * WW);
        float mean = S / n;
        float var  = fmaxf(SS / n - mean * mean, 0.f);
        stats[b * 64 + threadIdx.x] = make_float2(mean, rsqrtf(var + EPS));
    }
}

// ---------------- in-place normalize + relu on NHWC bf16 ----------------
__global__ __launch_bounds__(256) void norm_h(unsigned short* __restrict__ h,
                                              const float2* __restrict__ stats)
{
    __shared__ float2 st[64];
    const int b = blockIdx.y;
    if (threadIdx.x < 64) st[threadIdx.x] = stats[b * 64 + threadIdx.x];
    __syncthreads();
    size_t i = (size_t)blockIdx.x * 256 + threadIdx.x;   // bf16x8 chunk within b
    unsigned short* p = h + ((size_t)b * HH * WW * 64) + i * 8;
    int c0 = (int)((i & 7) * 8);
    bf16x8 v = *(bf16x8*)p;
    unsigned short res[8];
#pragma unroll
    for (int j = 0; j < 8; ++j) {
        float2 ms = st[c0 + j];
        res[j] = f2bf(fmaxf((bf2f(((unsigned short*)&v)[j]) - ms.x) * ms.y, 0.f));
    }
    *(bf16x8*)p = *(bf16x8*)res;
}

// ---------------- in-place normalize + relu on NCHW fp32 ----------------
__global__ __launch_bounds__(256) void finalize_kernel(float* __restrict__ out,
                                                       const float2* __restrict__ stats)
{
    const int bc  = blockIdx.x >> 2;
    const int seg = blockIdx.x & 3;
    float2 ms = stats[bc];
    float4* p = (float4*)(out + (size_t)bc * (HH * WW));
    const int n4 = HH * WW / 4;
    for (int i = seg * (n4 / 4) + threadIdx.x; i < (seg + 1) * (n4 / 4); i += 256) {
        float4 v = p[i];
        v.x = fmaxf((v.x - ms.x) * ms.y, 0.f);
        v.y = fmaxf((v.y - ms.x) * ms.y, 0.f);
        v.z = fmaxf((v.z - ms.x) * ms.y, 0.f);
        v.w = fmaxf((v.w - ms.x) * ms.y, 0.f);
        p[i] = v;
    }
}

extern "C" void kernel_launch(void* const* d_in, const int* in_sizes, int n_in,
                              void* d_out, int out_size, void* d_ws, size_t ws_size,
                              hipStream_t stream)
{
    const float* x  = (const float*)d_in[0];
    const float* w1 = (const float*)d_in[1];
    const float* b1 = (const float*)d_in[2];
    const float* w2 = (const float*)d_in[3];
    const float* b2 = (const float*)d_in[4];
    float* out = (float*)d_out;

    char* ws = (char*)d_ws;
    size_t off = 0;
    unsigned short* h_hwc = (unsigned short*)(ws + off); off += (size_t)BB * HH * WW * 64 * 2;
    unsigned short* x_hwc = (unsigned short*)(ws + off); off += (size_t)BB * HH * WW * 32 * 2;
    unsigned short* wt1   = (unsigned short*)(ws + off); off += 9 * 64 * 32 * 2;
    unsigned short* wt2   = (unsigned short*)(ws + off); off += 9 * 64 * 64 * 2;
    float2* partials      = (float2*)(ws + off);         off += (size_t)BB * 400 * 64 * sizeof(float2);
    float2* stats1        = (float2*)(ws + off);         off += 512 * sizeof(float2);
    float2* stats2        = (float2*)(ws + off);         off += 512 * sizeof(float2);

    dim3 cgrid(5, 80, BB);   // 64px x-tiles, 4-row y-tiles, batch

    prep_hwc<<<dim3(5, HH, BB), 256, 0, stream>>>(x, x_hwc);
    wprep_kernel<<<144, 256, 0, stream>>>(w1, w2, wt1, wt2);

    // conv1: raw conv -> NHWC bf16 h + stats partials
    conv_mfma<32, 1><<<cgrid, 256, 0, stream>>>(x_hwc, wt1, b1, h_hwc, nullptr, partials);
    reduce_stats<<<BB, 256, 0, stream>>>(partials, stats1);
    // normalize h in place (relu((h-mu)*rstd))
    norm_h<<<dim3(3200, BB), 256, 0, stream>>>(h_hwc, stats1);
    // conv2: normalized h -> raw conv NCHW fp32 out + stats partials (K-dbuf)
    conv_mfma<64, 0><<<cgrid, 256, 0, stream>>>(h_hwc, wt2, b2, nullptr, out, partials);
    reduce_stats<<<BB, 256, 0, stream>>>(partials, stats2);
    // in-place normalize + relu on d_out
    finalize_kernel<<<BB * 64 * 4, 256, 0, stream>>>(out, stats2);
}

// Round 7
// 356.926 us; speedup vs baseline: 2.1300x; 1.3444x over previous
//
#include <hip/hip_runtime.h>

#define HH 320
#define WW 320
#define BB 8
static constexpr float EPS = 1e-5f;

typedef __attribute__((ext_vector_type(8))) short bf16x8;
typedef __attribute__((ext_vector_type(4))) float f32x4;

__device__ inline float bf2f(unsigned short u) {
    union { unsigned int i; float f; } v; v.i = ((unsigned int)u) << 16; return v.f;
}
__device__ inline unsigned short f2bf(float f) {
    union { float f; unsigned int i; } v; v.f = f;
    unsigned int r = v.i + 0x7fffu + ((v.i >> 16) & 1u);
    return (unsigned short)(r >> 16);
}
__device__ inline void glds16(const void* g, void* l) {
    __builtin_amdgcn_global_load_lds(
        (const __attribute__((address_space(1))) unsigned int*)g,
        (__attribute__((address_space(3))) unsigned int*)l, 16, 0, 0);
}

// ---------------- NCHW fp32 -> NHWC bf16 (CIN=32) ----------------
__global__ __launch_bounds__(256) void prep_hwc(const float* __restrict__ in,
                                                unsigned short* __restrict__ out)
{
    __shared__ float sT[32][65];
    const int tid = threadIdx.x;
    const int x0  = blockIdx.x * 64;
    const int y   = blockIdx.y;
    const int b   = blockIdx.z;
    for (int e = tid; e < 32 * 64; e += 256) {
        int c = e >> 6, x = e & 63;
        sT[c][x] = in[(((size_t)(b * 32 + c) * HH) + y) * WW + x0 + x];
    }
    __syncthreads();
    for (int e = tid; e < 64 * 32; e += 256) {
        int x = e >> 5, c = e & 31;
        out[((((size_t)b * HH + y) * WW) + x0 + x) * 32 + c] = f2bf(sT[c][x]);
    }
}

// ---------------- implicit-GEMM conv 3x3 via MFMA ----------------
// Block: 4 waves, wave w owns output row y0+w. Tile: 4 rows x 64 px x 64 oc.
// Weights converted fp32->bf16 in-kernel and staged to swizzled LDS per chunk.
// A: NORM=0 -> global_load_lds (pre-swizzled source). NORM=1 -> reg-stage with
// fused relu((v-mean)*rstd), immediate consume (no live arrays across compute).
// Output: D[oc][px] (swapped mfma operands), short4 stores to NHWC bf16.
template<int CIN, int NORM>
__global__ __launch_bounds__(256, 2) void conv_mfma(
    const unsigned short* __restrict__ in_hwc,   // [B][H][W][CIN] bf16
    const float2* __restrict__ stats_in,         // [B*64] (NORM)
    const float* __restrict__ wsrc,              // [64][CIN][3][3] fp32 raw
    const float* __restrict__ bias,              // [64] fp32
    unsigned short* __restrict__ out_hwc,        // [B][H][W][64] bf16
    float2* __restrict__ partials)               // [B*400][64]
{
    constexpr int ICC = CIN / 32;

    __shared__ __align__(16) unsigned short sA[6 * 264 * 8];    // 25344 B
    __shared__ __align__(16) unsigned short sW[9 * 64 * 4 * 8]; // 36864 B
    __shared__ float sRedS[256];
    __shared__ float sRedSS[256];
    __shared__ float2 sStats[64];

    const int tid = threadIdx.x;
    const int x0  = blockIdx.x * 64;
    const int y0  = blockIdx.y * 4;
    const int b   = blockIdx.z;
    const int w   = tid >> 6;
    const int l   = tid & 63;
    const int lm  = l & 15;
    const int g   = l >> 4;

    if (NORM) {
        if (tid < 64) sStats[tid] = stats_in[b * 64 + tid];
    }

    f32x4 acc[4][4];
#pragma unroll
    for (int fx = 0; fx < 4; ++fx)
#pragma unroll
        for (int fn = 0; fn < 4; ++fn)
            acc[fx][fn] = (f32x4){0.f, 0.f, 0.f, 0.f};

    const int woc  = tid >> 2;        // 0..63
    const int wicq = tid & 3;         // 0..3
    const int wswz = (woc >> 1) & 3;

    for (int icc = 0; icc < ICC; ++icc) {
        __syncthreads();

        // ---- stage weights chunk: fp32 raw -> bf16 swizzled LDS ----
        {
            const float* wb = wsrc + ((size_t)woc * CIN + icc * 32 + wicq * 8) * 9;
#pragma unroll
            for (int kk = 0; kk < 9; ++kk) {
                unsigned short pk[8];
#pragma unroll
                for (int i = 0; i < 8; ++i) pk[i] = f2bf(wb[i * 9 + kk]);
                *(bf16x8*)&sW[((kk * 64 + woc) * 4 + (wicq ^ wswz)) * 8] = *(bf16x8*)pk;
            }
        }

        // ---- stage A tile + halo ----
        if (NORM == 0) {
            for (int r = w; r < 6; r += 4) {
                int gy = y0 + r - 1;
                unsigned short* ldsrow = sA + r * 2112;
                if ((unsigned)gy < HH) {
                    const unsigned short* rowbase =
                        in_hwc + ((size_t)(b * HH + gy) * WW) * CIN + icc * 32;
#pragma unroll
                    for (int i = 0; i < 4; ++i) {
                        int u  = 4 + i * 64 + l;           // dest 16B unit
                        int x  = u >> 2;                   // px slot 1..64
                        int cs = (u & 3) ^ ((x >> 1) & 3); // inverse swizzle on source
                        glds16(rowbase + (size_t)(x0 + x - 1) * CIN + cs * 8,
                               ldsrow + (size_t)(4 + i * 64) * 8);
                    }
                } else {
                    for (int u2 = l; u2 < 264; u2 += 64)
                        *(bf16x8*)(ldsrow + u2 * 8) = (bf16x8){0,0,0,0,0,0,0,0};
                }
            }
            if (tid < 48) {   // px slots 0 and 65 (swizzle identity there)
                int icq = tid & 3, side = (tid >> 2) & 1, r = tid >> 3;
                int xs = side ? 65 : 0;
                int gy = y0 + r - 1, gx = x0 + xs - 1;
                bf16x8 v = (bf16x8){0,0,0,0,0,0,0,0};
                if ((unsigned)gy < HH && (unsigned)gx < WW)
                    v = *(const bf16x8*)&in_hwc[(((size_t)(b * HH + gy) * WW) + gx) * CIN + icq * 8];
                *(bf16x8*)&sA[(r * 264 + xs * 4 + icq) * 8] = v;
            }
        } else {
#pragma unroll
            for (int k = 0; k < 7; ++k) {
                int e = tid + k * 256;
                if (e < 1584) {
                    int r = e / 264, rem = e - r * 264;
                    int x = rem >> 2, icq = rem & 3;
                    int gy = y0 + r - 1, gx = x0 + x - 1;
                    bf16x8 v = (bf16x8){0,0,0,0,0,0,0,0};
                    if ((unsigned)gy < HH && (unsigned)gx < WW)
                        v = *(const bf16x8*)&in_hwc[(((size_t)(b * HH + gy) * WW) + gx) * CIN + icc * 32 + icq * 8];
                    unsigned short res[8];
#pragma unroll
                    for (int j = 0; j < 8; ++j) {
                        float2 ms = sStats[icc * 32 + icq * 8 + j];
                        res[j] = f2bf(fmaxf((bf2f(((unsigned short*)&v)[j]) - ms.x) * ms.y, 0.f));
                    }
                    *(bf16x8*)&sA[(r * 264 + x * 4 + (icq ^ ((x >> 1) & 3))) * 8] = *(bf16x8*)res;
                }
            }
        }
        __syncthreads();

        // ---- compute ----
#pragma unroll
        for (int kk = 0; kk < 9; ++kk) {
            const int ky = kk / 3, kx = kk - ky * 3;
            bf16x8 af[4], bfr[4];
#pragma unroll
            for (int fx = 0; fx < 4; ++fx) {
                int xl = fx * 16 + lm + kx;
                int u  = (xl * 4 + g) ^ ((xl >> 1) & 3);
                af[fx] = *(const bf16x8*)&sA[((w + ky) * 264 + u) * 8];
            }
#pragma unroll
            for (int fn = 0; fn < 4; ++fn) {
                int ocr = fn * 16 + lm;
                int p   = (kk * 64 + ocr) * 4 + (g ^ ((ocr >> 1) & 3));
                bfr[fn] = *(const bf16x8*)&sW[p * 8];
            }
#pragma unroll
            for (int fn = 0; fn < 4; ++fn)
#pragma unroll
                for (int fx = 0; fx < 4; ++fx)
                    acc[fx][fn] = __builtin_amdgcn_mfma_f32_16x16x32_bf16(
                        bfr[fn], af[fx], acc[fx][fn], 0, 0, 0);
        }
    }

    // ---- epilogue: lane holds oc = 16*fo + 4g + j, px = x0 + 16*fp + lm ----
    const int row = y0 + w;
#pragma unroll
    for (int fo = 0; fo < 4; ++fo) {
        float4 b4 = *(const float4*)&bias[fo * 16 + g * 4];
        float bb[4] = {b4.x, b4.y, b4.z, b4.w};
        float sj[4] = {0,0,0,0}, qj[4] = {0,0,0,0};
#pragma unroll
        for (int fp = 0; fp < 4; ++fp) {
            unsigned short pk[4];
#pragma unroll
            for (int j = 0; j < 4; ++j) {
                float v = acc[fp][fo][j] + bb[j];
                sj[j] += v; qj[j] += v * v;
                pk[j] = f2bf(v);
            }
            *(short4*)&out_hwc[(((size_t)b * HH + row) * WW + x0 + fp * 16 + lm) * 64 + fo * 16 + g * 4] =
                *(short4*)pk;
        }
#pragma unroll
        for (int m = 1; m <= 8; m <<= 1)
#pragma unroll
            for (int j = 0; j < 4; ++j) {
                sj[j] += __shfl_xor(sj[j], m);
                qj[j] += __shfl_xor(qj[j], m);
            }
        if (lm == 0) {
#pragma unroll
            for (int j = 0; j < 4; ++j) {
                sRedS [w * 64 + fo * 16 + g * 4 + j] = sj[j];
                sRedSS[w * 64 + fo * 16 + g * 4 + j] = qj[j];
            }
        }
    }
    __syncthreads();
    if (tid < 64) {
        float S = 0.f, SS = 0.f;
#pragma unroll
        for (int q = 0; q < 4; ++q) { S += sRedS[q * 64 + tid]; SS += sRedSS[q * 64 + tid]; }
        partials[((size_t)b * 400 + blockIdx.y * 5 + blockIdx.x) * 64 + tid] = make_float2(S, SS);
    }
}

// ---------------- partials -> (mean, rstd) ----------------
__global__ __launch_bounds__(256) void reduce_stats(const float2* __restrict__ partials,
                                                    float2* __restrict__ stats)
{
    const int b  = blockIdx.x;
    const int oc = threadIdx.x & 63;
    const int q  = threadIdx.x >> 6;
    float s = 0.f, ss = 0.f;
    for (int i = q; i < 400; i += 4) {
        float2 p = partials[((size_t)b * 400 + i) * 64 + oc];
        s += p.x; ss += p.y;
    }
    __shared__ float2 red[4][64];
    red[q][oc] = make_float2(s, ss);
    __syncthreads();
    if (threadIdx.x < 64) {
        float S = 0.f, SS = 0.f;
#pragma unroll
        for (int k = 0; k < 4; ++k) { S += red[k][threadIdx.x].x; SS += red[k][threadIdx.x].y; }
        const float n = (float)(HH * WW);
        float mean = S / n;
        float var  = fmaxf(SS / n - mean * mean, 0.f);
        stats[b * 64 + threadIdx.x] = make_float2(mean, rsqrtf(var + EPS));
    }
}

// ------- final: read h2 NHWC bf16, norm+relu, register-transpose, NCHW fp32 -------
__global__ __launch_bounds__(256) void finalize_t(const unsigned short* __restrict__ h2,
                                                  const float2* __restrict__ stats,
                                                  float* __restrict__ out)
{
    __shared__ float2 sSt[64];
    const int tid = threadIdx.x;
    const int b   = blockIdx.z;
    if (tid < 64) sSt[tid] = stats[b * 64 + tid];
    __syncthreads();
    const int r   = tid >> 6;
    const int px  = tid & 63;
    const int row = blockIdx.y * 4 + r;
    const int x   = blockIdx.x * 64 + px;
    const unsigned short* src = h2 + ((size_t)(b * HH + row) * WW + x) * 64;
    bf16x8 v[8];
#pragma unroll
    for (int cq = 0; cq < 8; ++cq) v[cq] = *(const bf16x8*)(src + cq * 8);
#pragma unroll
    for (int cq = 0; cq < 8; ++cq)
#pragma unroll
        for (int j = 0; j < 8; ++j) {
            int c = cq * 8 + j;
            float2 ms = sSt[c];
            float f = fmaxf((bf2f(((unsigned short*)&v[cq])[j]) - ms.x) * ms.y, 0.f);
            out[((size_t)(b * 64 + c) * HH + row) * WW + x] = f;
        }
}

extern "C" void kernel_launch(void* const* d_in, const int* in_sizes, int n_in,
                              void* d_out, int out_size, void* d_ws, size_t ws_size,
                              hipStream_t stream)
{
    const float* x  = (const float*)d_in[0];
    const float* w1 = (const float*)d_in[1];
    const float* b1 = (const float*)d_in[2];
    const float* w2 = (const float*)d_in[3];
    const float* b2 = (const float*)d_in[4];
    float* out = (float*)d_out;

    // ws layout (total 211,361,792 B == round-1 proven budget):
    // [0, 105MB)         h   : conv1 raw out, NHWC bf16
    // [+1638400)         partials (reused by both convs, sequentially)
    // [+4096, +4096)     stats1, stats2
    // [.., +105MB)       region2: x_hwc (52MB, dead after conv1) then h2 (105MB)
    char* ws = (char*)d_ws;
    unsigned short* h    = (unsigned short*)ws;
    float2* partials     = (float2*)(ws + 104857600);
    float2* stats1       = (float2*)(ws + 104857600 + 1638400);
    float2* stats2       = (float2*)(ws + 104857600 + 1638400 + 4096);
    unsigned short* reg2 = (unsigned short*)(ws + 104857600 + 1638400 + 8192);
    unsigned short* x_hwc = reg2;
    unsigned short* h2    = reg2;

    dim3 cgrid(5, 80, BB);

    prep_hwc<<<dim3(5, HH, BB), 256, 0, stream>>>(x, x_hwc);
    // conv1: raw conv -> h (NHWC bf16) + partials
    conv_mfma<32, 0><<<cgrid, 256, 0, stream>>>(x_hwc, nullptr, w1, b1, h, partials);
    reduce_stats<<<BB, 256, 0, stream>>>(partials, stats1);
    // conv2: fused norm(stats1)+relu on staging -> h2 (NHWC bf16) + partials
    conv_mfma<64, 1><<<cgrid, 256, 0, stream>>>(h, stats1, w2, b2, h2, partials);
    reduce_stats<<<BB, 256, 0, stream>>>(partials, stats2);
    // norm(stats2)+relu + transpose -> d_out fp32 NCHW
    finalize_t<<<dim3(5, 80, BB), 256, 0, stream>>>(h2, stats2, out);
}

// Round 8
// 339.680 us; speedup vs baseline: 2.2381x; 1.0508x over previous
//
#include <hip/hip_runtime.h>

#define HH 320
#define WW 320
#define BB 8
static constexpr float EPS = 1e-5f;

typedef __attribute__((ext_vector_type(8))) short bf16x8;
typedef __attribute__((ext_vector_type(4))) float f32x4;

__device__ inline float bf2f(unsigned short u) {
    union { unsigned int i; float f; } v; v.i = ((unsigned int)u) << 16; return v.f;
}
__device__ inline unsigned short f2bf(float f) {
    union { float f; unsigned int i; } v; v.f = f;
    unsigned int r = v.i + 0x7fffu + ((v.i >> 16) & 1u);
    return (unsigned short)(r >> 16);
}
__device__ inline void glds16(const void* g, void* l) {
    __builtin_amdgcn_global_load_lds(
        (const __attribute__((address_space(1))) unsigned int*)g,
        (__attribute__((address_space(3))) unsigned int*)l, 16, 0, 0);
}

// ---------------- NCHW fp32 -> NHWC bf16 (CIN=32) ----------------
__global__ __launch_bounds__(256) void prep_hwc(const float* __restrict__ in,
                                                unsigned short* __restrict__ out)
{
    __shared__ float sT[32][65];
    const int tid = threadIdx.x;
    const int x0  = blockIdx.x * 64;
    const int y   = blockIdx.y;
    const int b   = blockIdx.z;
    for (int e = tid; e < 32 * 64; e += 256) {
        int c = e >> 6, x = e & 63;
        sT[c][x] = in[(((size_t)(b * 32 + c) * HH) + y) * WW + x0 + x];
    }
    __syncthreads();
    for (int e = tid; e < 64 * 32; e += 256) {
        int x = e >> 5, c = e & 31;
        out[((((size_t)b * HH + y) * WW) + x0 + x) * 32 + c] = f2bf(sT[c][x]);
    }
}

// ------ weights OIHW fp32 -> bank-swizzled bf16 LDS image, glds-ready ------
// unit p = (kk*64 + oc)*4 + (icq ^ ((oc>>1)&3)); content = w[oc][ic0+icq*8+j][kk]
__global__ __launch_bounds__(256) void wprep_swz(const float* __restrict__ w1,
                                                 const float* __restrict__ w2,
                                                 unsigned short* __restrict__ wt1,
                                                 unsigned short* __restrict__ wt2)
{
    int i = blockIdx.x * 256 + threadIdx.x;
    if (i < 2304) {                       // wt1 (CIN=32), one chunk
        int s = i & 3, oc = (i >> 2) & 63, kk = i >> 8;
        int icq = s ^ ((oc >> 1) & 3);
        const float* src = w1 + ((size_t)oc * 32 + icq * 8) * 9 + kk;
        unsigned short pk[8];
#pragma unroll
        for (int j = 0; j < 8; ++j) pk[j] = f2bf(src[j * 9]);
        *(bf16x8*)&wt1[(size_t)i * 8] = *(bf16x8*)pk;
    }
    if (i < 4608) {                       // wt2 (CIN=64), two chunks [icc][2304]
        int icc = i / 2304, u = i - icc * 2304;
        int s = u & 3, oc = (u >> 2) & 63, kk = u >> 8;
        int icq = s ^ ((oc >> 1) & 3);
        const float* src = w2 + ((size_t)oc * 64 + icc * 32 + icq * 8) * 9 + kk;
        unsigned short pk[8];
#pragma unroll
        for (int j = 0; j < 8; ++j) pk[j] = f2bf(src[j * 9]);
        *(bf16x8*)&wt2[(size_t)i * 8] = *(bf16x8*)pk;
    }
}

// ---------------- implicit-GEMM conv 3x3 via MFMA ----------------
// Block: 4 waves, wave w owns output row y0+w. Tile: 4 rows x 64 px x 64 oc.
// sW staged per icc via 9 linear glds16/lane from the pre-swizzled wt image.
// sA: NORM=0 -> glds16 (source pre-permuted for bank swizzle);
//     NORM=1 -> reg-stage with fused relu((v-mean)*rstd), immediate consume.
// Output: D[oc][px] (swapped mfma operands), short4 stores to NHWC bf16.
template<int CIN, int NORM>
__global__ __launch_bounds__(256, 2) void conv_mfma(
    const unsigned short* __restrict__ in_hwc,   // [B][H][W][CIN] bf16
    const float2* __restrict__ stats_in,         // [B*64] (NORM)
    const unsigned short* __restrict__ wt,       // [ICC][2304 units] bf16 swizzled
    const float* __restrict__ bias,              // [64] fp32
    unsigned short* __restrict__ out_hwc,        // [B][H][W][64] bf16
    float2* __restrict__ partials)               // [B*400][64]
{
    constexpr int ICC = CIN / 32;

    __shared__ __align__(16) unsigned short sA[6 * 264 * 8];    // 25344 B
    __shared__ __align__(16) unsigned short sW[2304 * 8];       // 36864 B
    __shared__ float sRedS[256];
    __shared__ float sRedSS[256];
    __shared__ float2 sStats[64];

    const int tid = threadIdx.x;
    const int x0  = blockIdx.x * 64;
    const int y0  = blockIdx.y * 4;
    const int b   = blockIdx.z;
    const int w   = tid >> 6;
    const int l   = tid & 63;
    const int lm  = l & 15;
    const int g   = l >> 4;

    if (NORM) {
        if (tid < 64) sStats[tid] = stats_in[b * 64 + tid];
    }

    f32x4 acc[4][4];
#pragma unroll
    for (int fx = 0; fx < 4; ++fx)
#pragma unroll
        for (int fn = 0; fn < 4; ++fn)
            acc[fx][fn] = (f32x4){0.f, 0.f, 0.f, 0.f};

    for (int icc = 0; icc < ICC; ++icc) {
        __syncthreads();

        // ---- stage weights: 2304 linear units, wave w owns [w*576, w*576+576) ----
        {
            const unsigned short* wsrc = wt + (size_t)icc * 2304 * 8;
            const int base = w * 576;
#pragma unroll
            for (int i = 0; i < 9; ++i)
                glds16(wsrc + (size_t)(base + i * 64 + l) * 8,
                       sW + (size_t)(base + i * 64) * 8);
        }

        // ---- stage A tile + halo ----
        if (NORM == 0) {
            for (int r = w; r < 6; r += 4) {
                int gy = y0 + r - 1;
                unsigned short* ldsrow = sA + r * 2112;
                if ((unsigned)gy < HH) {
                    const unsigned short* rowbase =
                        in_hwc + ((size_t)(b * HH + gy) * WW) * CIN + icc * 32;
#pragma unroll
                    for (int i = 0; i < 4; ++i) {
                        int u  = 4 + i * 64 + l;           // dest 16B unit
                        int x  = u >> 2;                   // px slot 1..64
                        int cs = (u & 3) ^ ((x >> 1) & 3); // inverse swizzle on source
                        glds16(rowbase + (size_t)(x0 + x - 1) * CIN + cs * 8,
                               ldsrow + (size_t)(4 + i * 64) * 8);
                    }
                } else {
                    for (int u2 = l; u2 < 264; u2 += 64)
                        *(bf16x8*)(ldsrow + u2 * 8) = (bf16x8){0,0,0,0,0,0,0,0};
                }
            }
            if (tid < 48) {   // px slots 0 and 65 (swizzle identity there)
                int icq = tid & 3, side = (tid >> 2) & 1, r = tid >> 3;
                int xs = side ? 65 : 0;
                int gy = y0 + r - 1, gx = x0 + xs - 1;
                bf16x8 v = (bf16x8){0,0,0,0,0,0,0,0};
                if ((unsigned)gy < HH && (unsigned)gx < WW)
                    v = *(const bf16x8*)&in_hwc[(((size_t)(b * HH + gy) * WW) + gx) * CIN + icc * 32 + icq * 8];
                *(bf16x8*)&sA[(r * 264 + xs * 4 + icq) * 8] = v;
            }
        } else {
#pragma unroll
            for (int k = 0; k < 7; ++k) {
                int e = tid + k * 256;
                if (e < 1584) {
                    int r = e / 264, rem = e - r * 264;
                    int x = rem >> 2, icq = rem & 3;
                    int gy = y0 + r - 1, gx = x0 + x - 1;
                    bf16x8 v = (bf16x8){0,0,0,0,0,0,0,0};
                    if ((unsigned)gy < HH && (unsigned)gx < WW)
                        v = *(const bf16x8*)&in_hwc[(((size_t)(b * HH + gy) * WW) + gx) * CIN + icc * 32 + icq * 8];
                    unsigned short res[8];
#pragma unroll
                    for (int j = 0; j < 8; ++j) {
                        float2 ms = sStats[icc * 32 + icq * 8 + j];
                        res[j] = f2bf(fmaxf((bf2f(((unsigned short*)&v)[j]) - ms.x) * ms.y, 0.f));
                    }
                    *(bf16x8*)&sA[(r * 264 + x * 4 + (icq ^ ((x >> 1) & 3))) * 8] = *(bf16x8*)res;
                }
            }
        }
        __syncthreads();

        // ---- compute ----
#pragma unroll
        for (int kk = 0; kk < 9; ++kk) {
            const int ky = kk / 3, kx = kk - ky * 3;
            bf16x8 af[4], bfr[4];
#pragma unroll
            for (int fx = 0; fx < 4; ++fx) {
                int xl = fx * 16 + lm + kx;
                int u  = (xl * 4 + g) ^ ((xl >> 1) & 3);
                af[fx] = *(const bf16x8*)&sA[((w + ky) * 264 + u) * 8];
            }
#pragma unroll
            for (int fn = 0; fn < 4; ++fn) {
                int ocr = fn * 16 + lm;
                int p   = (kk * 64 + ocr) * 4 + (g ^ ((ocr >> 1) & 3));
                bfr[fn] = *(const bf16x8*)&sW[p * 8];
            }
#pragma unroll
            for (int fn = 0; fn < 4; ++fn)
#pragma unroll
                for (int fx = 0; fx < 4; ++fx)
                    acc[fx][fn] = __builtin_amdgcn_mfma_f32_16x16x32_bf16(
                        bfr[fn], af[fx], acc[fx][fn], 0, 0, 0);
        }
    }

    // ---- epilogue: lane holds oc = 16*fo + 4g + j, px = x0 + 16*fp + lm ----
    const int row = y0 + w;
#pragma unroll
    for (int fo = 0; fo < 4; ++fo) {
        float4 b4 = *(const float4*)&bias[fo * 16 + g * 4];
        float bb[4] = {b4.x, b4.y, b4.z, b4.w};
        float sj[4] = {0,0,0,0}, qj[4] = {0,0,0,0};
#pragma unroll
        for (int fp = 0; fp < 4; ++fp) {
            unsigned short pk[4];
#pragma unroll
            for (int j = 0; j < 4; ++j) {
                float v = acc[fp][fo][j] + bb[j];
                sj[j] += v; qj[j] += v * v;
                pk[j] = f2bf(v);
            }
            *(short4*)&out_hwc[(((size_t)b * HH + row) * WW + x0 + fp * 16 + lm) * 64 + fo * 16 + g * 4] =
                *(short4*)pk;
        }
#pragma unroll
        for (int m = 1; m <= 8; m <<= 1)
#pragma unroll
            for (int j = 0; j < 4; ++j) {
                sj[j] += __shfl_xor(sj[j], m);
                qj[j] += __shfl_xor(qj[j], m);
            }
        if (lm == 0) {
#pragma unroll
            for (int j = 0; j < 4; ++j) {
                sRedS [w * 64 + fo * 16 + g * 4 + j] = sj[j];
                sRedSS[w * 64 + fo * 16 + g * 4 + j] = qj[j];
            }
        }
    }
    __syncthreads();
    if (tid < 64) {
        float S = 0.f, SS = 0.f;
#pragma unroll
        for (int q = 0; q < 4; ++q) { S += sRedS[q * 64 + tid]; SS += sRedSS[q * 64 + tid]; }
        partials[((size_t)b * 400 + blockIdx.y * 5 + blockIdx.x) * 64 + tid] = make_float2(S, SS);
    }
}

// ---------------- partials -> (mean, rstd) ----------------
__global__ __launch_bounds__(256) void reduce_stats(const float2* __restrict__ partials,
                                                    float2* __restrict__ stats)
{
    const int b  = blockIdx.x;
    const int oc = threadIdx.x & 63;
    const int q  = threadIdx.x >> 6;
    float s = 0.f, ss = 0.f;
    for (int i = q; i < 400; i += 4) {
        float2 p = partials[((size_t)b * 400 + i) * 64 + oc];
        s += p.x; ss += p.y;
    }
    __shared__ float2 red[4][64];
    red[q][oc] = make_float2(s, ss);
    __syncthreads();
    if (threadIdx.x < 64) {
        float S = 0.f, SS = 0.f;
#pragma unroll
        for (int k = 0; k < 4; ++k) { S += red[k][threadIdx.x].x; SS += red[k][threadIdx.x].y; }
        const float n = (float)(HH * WW);
        float mean = S / n;
        float var  = fmaxf(SS / n - mean * mean, 0.f);
        stats[b * 64 + threadIdx.x] = make_float2(mean, rsqrtf(var + EPS));
    }
}

// ------- final: read h2 NHWC bf16, norm+relu, register-transpose, NCHW fp32 -------
__global__ __launch_bounds__(256) void finalize_t(const unsigned short* __restrict__ h2,
                                                  const float2* __restrict__ stats,
                                                  float* __restrict__ out)
{
    __shared__ float2 sSt[64];
    const int tid = threadIdx.x;
    const int b   = blockIdx.z;
    if (tid < 64) sSt[tid] = stats[b * 64 + tid];
    __syncthreads();
    const int r   = tid >> 6;
    const int px  = tid & 63;
    const int row = blockIdx.y * 4 + r;
    const int x   = blockIdx.x * 64 + px;
    const unsigned short* src = h2 + ((size_t)(b * HH + row) * WW + x) * 64;
    bf16x8 v[8];
#pragma unroll
    for (int cq = 0; cq < 8; ++cq) v[cq] = *(const bf16x8*)(src + cq * 8);
#pragma unroll
    for (int cq = 0; cq < 8; ++cq)
#pragma unroll
        for (int j = 0; j < 8; ++j) {
            int c = cq * 8 + j;
            float2 ms = sSt[c];
            float f = fmaxf((bf2f(((unsigned short*)&v[cq])[j]) - ms.x) * ms.y, 0.f);
            out[((size_t)(b * 64 + c) * HH + row) * WW + x] = f;
        }
}

extern "C" void kernel_launch(void* const* d_in, const int* in_sizes, int n_in,
                              void* d_out, int out_size, void* d_ws, size_t ws_size,
                              hipStream_t stream)
{
    const float* x  = (const float*)d_in[0];
    const float* w1 = (const float*)d_in[1];
    const float* b1 = (const float*)d_in[2];
    const float* w2 = (const float*)d_in[3];
    const float* b2 = (const float*)d_in[4];
    float* out = (float*)d_out;

    // ws layout (211,361,792 B total == round-7 proven budget):
    char* ws = (char*)d_ws;
    unsigned short* h    = (unsigned short*)ws;                         // 105 MB NHWC bf16
    float2* partials     = (float2*)(ws + 104857600);                   // 1.6 MB
    float2* stats1       = (float2*)(ws + 104857600 + 1638400);
    float2* stats2       = (float2*)(ws + 104857600 + 1638400 + 4096);
    unsigned short* reg2 = (unsigned short*)(ws + 104857600 + 1638400 + 8192);
    unsigned short* x_hwc = reg2;   // 52 MB, dead after conv1
    unsigned short* h2    = reg2;   // 105 MB, conv2 output

    // prepped weights live in the tail of d_out (dead until finalize_t rewrites all of it)
    // d_out = 209,715,200 B; wt2 at end (73,728 B), wt1 before it (36,864 B)
    unsigned short* wt2 = (unsigned short*)((char*)d_out + 209715200 - 73728);
    unsigned short* wt1 = (unsigned short*)((char*)d_out + 209715200 - 73728 - 36864);

    dim3 cgrid(5, 80, BB);

    wprep_swz<<<18, 256, 0, stream>>>(w1, w2, wt1, wt2);
    prep_hwc<<<dim3(5, HH, BB), 256, 0, stream>>>(x, x_hwc);

    // conv1: raw conv -> h (NHWC bf16) + partials
    conv_mfma<32, 0><<<cgrid, 256, 0, stream>>>(x_hwc, nullptr, wt1, b1, h, partials);
    reduce_stats<<<BB, 256, 0, stream>>>(partials, stats1);
    // conv2: fused norm(stats1)+relu on staging -> h2 (NHWC bf16) + partials
    conv_mfma<64, 1><<<cgrid, 256, 0, stream>>>(h, stats1, wt2, b2, h2, partials);
    reduce_stats<<<BB, 256, 0, stream>>>(partials, stats2);
    // norm(stats2)+relu + transpose -> d_out fp32 NCHW (fully rewrites d_out)
    finalize_t<<<dim3(5, 80, BB), 256, 0, stream>>>(h2, stats2, out);
}

// Round 9
// 332.623 us; speedup vs baseline: 2.2856x; 1.0212x over previous
//
#include <hip/hip_runtime.h>

#define HH 320
#define WW 320
#define BB 8
static constexpr float EPS = 1e-5f;

typedef __attribute__((ext_vector_type(8))) short bf16x8;
typedef __attribute__((ext_vector_type(4))) float f32x4;

__device__ inline float bf2f(unsigned short u) {
    union { unsigned int i; float f; } v; v.i = ((unsigned int)u) << 16; return v.f;
}
__device__ inline unsigned short f2bf(float f) {
    union { float f; unsigned int i; } v; v.f = f;
    unsigned int r = v.i + 0x7fffu + ((v.i >> 16) & 1u);
    return (unsigned short)(r >> 16);
}
__device__ inline void glds16(const void* g, void* l) {
    __builtin_amdgcn_global_load_lds(
        (const __attribute__((address_space(1))) unsigned int*)g,
        (__attribute__((address_space(3))) unsigned int*)l, 16, 0, 0);
}

// ---------------- NCHW fp32 -> NHWC bf16 (CIN=32) ----------------
__global__ __launch_bounds__(256) void prep_hwc(const float* __restrict__ in,
                                                unsigned short* __restrict__ out)
{
    __shared__ float sT[32][65];
    const int tid = threadIdx.x;
    const int x0  = blockIdx.x * 64;
    const int y   = blockIdx.y;
    const int b   = blockIdx.z;
    for (int e = tid; e < 32 * 64; e += 256) {
        int c = e >> 6, x = e & 63;
        sT[c][x] = in[(((size_t)(b * 32 + c) * HH) + y) * WW + x0 + x];
    }
    __syncthreads();
    for (int e = tid; e < 64 * 32; e += 256) {
        int x = e >> 5, c = e & 31;
        out[((((size_t)b * HH + y) * WW) + x0 + x) * 32 + c] = f2bf(sT[c][x]);
    }
}

// ------ weights OIHW fp32 -> bank-swizzled bf16 LDS image, glds-ready ------
__global__ __launch_bounds__(256) void wprep_swz(const float* __restrict__ w1,
                                                 const float* __restrict__ w2,
                                                 unsigned short* __restrict__ wt1,
                                                 unsigned short* __restrict__ wt2)
{
    int i = blockIdx.x * 256 + threadIdx.x;
    if (i < 2304) {
        int s = i & 3, oc = (i >> 2) & 63, kk = i >> 8;
        int icq = s ^ ((oc >> 1) & 3);
        const float* src = w1 + ((size_t)oc * 32 + icq * 8) * 9 + kk;
        unsigned short pk[8];
#pragma unroll
        for (int j = 0; j < 8; ++j) pk[j] = f2bf(src[j * 9]);
        *(bf16x8*)&wt1[(size_t)i * 8] = *(bf16x8*)pk;
    }
    if (i < 4608) {
        int icc = i / 2304, u = i - icc * 2304;
        int s = u & 3, oc = (u >> 2) & 63, kk = u >> 8;
        int icq = s ^ ((oc >> 1) & 3);
        const float* src = w2 + ((size_t)oc * 64 + icc * 32 + icq * 8) * 9 + kk;
        unsigned short pk[8];
#pragma unroll
        for (int j = 0; j < 8; ++j) pk[j] = f2bf(src[j * 9]);
        *(bf16x8*)&wt2[(size_t)i * 8] = *(bf16x8*)pk;
    }
}

// ============ conv1: ring-buffered y-supertile, pipelined (CIN=32) ============
// Block = 4 waves, 16 output rows (4 sub-tiles of 4 rows), 64 px, 64 oc.
// sA = 10-row ring (42 KB); sW staged once (36 KB). Step t: issue stage(t+1)
// glds -> compute(t) -> stores -> barrier. Stats accumulate in regs; one
// partial per block. Output D[oc][px] via swapped mfma, short4 NHWC stores.
__global__ __launch_bounds__(256, 2) void conv1_ring(
    const unsigned short* __restrict__ in_hwc,   // [B][H][W][32] bf16
    const unsigned short* __restrict__ wt,       // [2304 units] bf16 swizzled
    const float* __restrict__ bias,              // [64]
    unsigned short* __restrict__ out_hwc,        // [B][H][W][64] bf16
    float2* __restrict__ partials)               // [B*100][64]
{
    __shared__ __align__(16) unsigned short sA[10 * 264 * 8];   // 42240 B ring
    __shared__ __align__(16) unsigned short sW[2304 * 8];       // 36864 B
    __shared__ float sRedS[256];
    __shared__ float sRedSS[256];

    const int tid = threadIdx.x;
    const int x0  = blockIdx.x * 64;
    const int yb  = blockIdx.y * 16;
    const int b   = blockIdx.z;
    const int w   = tid >> 6;
    const int l   = tid & 63;
    const int lm  = l & 15;
    const int g   = l >> 4;

    // ---- stage weights once ----
    {
        const int base = w * 576;
#pragma unroll
        for (int i = 0; i < 9; ++i)
            glds16(wt + (size_t)(base + i * 64 + l) * 8,
                   sW + (size_t)(base + i * 64) * 8);
    }

    // stage one input row (local row rl, ring slot) — called by one wave
    auto stage_row = [&](int rl, int slot) {
        int gy = yb - 1 + rl;
        unsigned short* ldsrow = sA + slot * 2112;
        if ((unsigned)gy < HH) {
            const unsigned short* rowbase = in_hwc + ((size_t)(b * HH + gy) * WW) * 32;
#pragma unroll
            for (int i = 0; i < 4; ++i) {
                int u  = 4 + i * 64 + l;
                int x  = u >> 2;
                int cs = (u & 3) ^ ((x >> 1) & 3);
                glds16(rowbase + (size_t)(x0 + x - 1) * 32 + cs * 8,
                       ldsrow + (size_t)(4 + i * 64) * 8);
            }
            if (l < 8) {          // px slots 0 and 65 (swizzle identity there)
                int icq = l & 3, side = l >> 2;
                int xs = side ? 65 : 0;
                int gx = x0 + xs - 1;
                bf16x8 v = (bf16x8){0,0,0,0,0,0,0,0};
                if ((unsigned)gx < WW)
                    v = *(const bf16x8*)&in_hwc[(((size_t)(b * HH + gy) * WW) + gx) * 32 + icq * 8];
                *(bf16x8*)(ldsrow + (xs * 4 + icq) * 8) = v;
            }
        } else {
            for (int u2 = l; u2 < 264; u2 += 64)
                *(bf16x8*)(ldsrow + u2 * 8) = (bf16x8){0,0,0,0,0,0,0,0};
        }
    };

    f32x4 acc[4][4];
#pragma unroll
    for (int fp = 0; fp < 4; ++fp)
#pragma unroll
        for (int fo = 0; fo < 4; ++fo)
            acc[fp][fo] = (f32x4){0.f, 0.f, 0.f, 0.f};

    float bb[4][4];     // bias per (fo, j): oc = 16*fo + 4g + j
#pragma unroll
    for (int fo = 0; fo < 4; ++fo) {
        float4 b4 = *(const float4*)&bias[fo * 16 + g * 4];
        bb[fo][0] = b4.x; bb[fo][1] = b4.y; bb[fo][2] = b4.z; bb[fo][3] = b4.w;
    }
    float sjA[4][4] = {}, qjA[4][4] = {};

    // ---- prologue: stage local rows 0..5 ----
    stage_row(w, w);
    if (w < 2) stage_row(4 + w, 4 + w);
    __syncthreads();

    // one pipeline step: stage rows for sub-tile tn (if any), compute+store sub-tile t
    auto step = [&](int t, bool do_stage) {
        if (do_stage) {
            int rl = 4 * (t + 1) + 2 + w;                 // rows 4t+6 .. 4t+9
            int slot = rl - (rl >= 10 ? 10 : 0);
            stage_row(rl, slot);
        }
        // ---- compute sub-tile t ----
#pragma unroll
        for (int kk = 0; kk < 9; ++kk) {
            const int ky = kk / 3, kx = kk - ky * 3;
            int rl = 4 * t + w + ky;
            int slot = rl - (rl >= 10 ? 10 : 0);
            const unsigned short* rowp = sA + slot * 2112;
            bf16x8 af[4], bfr[4];
#pragma unroll
            for (int fp = 0; fp < 4; ++fp) {
                int xl = fp * 16 + lm + kx;
                int u  = (xl * 4 + g) ^ ((xl >> 1) & 3);
                af[fp] = *(const bf16x8*)(rowp + u * 8);
            }
#pragma unroll
            for (int fo = 0; fo < 4; ++fo) {
                int ocr = fo * 16 + lm;
                int p   = (kk * 64 + ocr) * 4 + (g ^ ((ocr >> 1) & 3));
                bfr[fo] = *(const bf16x8*)&sW[p * 8];
            }
#pragma unroll
            for (int fo = 0; fo < 4; ++fo)
#pragma unroll
                for (int fp = 0; fp < 4; ++fp)
                    acc[fp][fo] = __builtin_amdgcn_mfma_f32_16x16x32_bf16(
                        bfr[fo], af[fp], acc[fp][fo], 0, 0, 0);
        }
        // ---- store + stats accumulate, reset acc ----
        const int row = yb + 4 * t + w;
#pragma unroll
        for (int fo = 0; fo < 4; ++fo) {
#pragma unroll
            for (int fp = 0; fp < 4; ++fp) {
                unsigned short pk[4];
#pragma unroll
                for (int j = 0; j < 4; ++j) {
                    float v = acc[fp][fo][j] + bb[fo][j];
                    sjA[fo][j] += v; qjA[fo][j] += v * v;
                    pk[j] = f2bf(v);
                }
                *(short4*)&out_hwc[(((size_t)b * HH + row) * WW + x0 + fp * 16 + lm) * 64 + fo * 16 + g * 4] =
                    *(short4*)pk;
                acc[fp][fo] = (f32x4){0.f, 0.f, 0.f, 0.f};
            }
        }
        __syncthreads();
    };

    step(0, true);
    step(1, true);
    step(2, true);
    step(3, false);

    // ---- block-level stats partial ----
#pragma unroll
    for (int fo = 0; fo < 4; ++fo) {
#pragma unroll
        for (int m = 1; m <= 8; m <<= 1)
#pragma unroll
            for (int j = 0; j < 4; ++j) {
                sjA[fo][j] += __shfl_xor(sjA[fo][j], m);
                qjA[fo][j] += __shfl_xor(qjA[fo][j], m);
            }
        if (lm == 0) {
#pragma unroll
            for (int j = 0; j < 4; ++j) {
                sRedS [w * 64 + fo * 16 + g * 4 + j] = sjA[fo][j];
                sRedSS[w * 64 + fo * 16 + g * 4 + j] = qjA[fo][j];
            }
        }
    }
    __syncthreads();
    if (tid < 64) {
        float S = 0.f, SS = 0.f;
#pragma unroll
        for (int q = 0; q < 4; ++q) { S += sRedS[q * 64 + tid]; SS += sRedSS[q * 64 + tid]; }
        partials[((size_t)b * 100 + blockIdx.y * 5 + blockIdx.x) * 64 + tid] = make_float2(S, SS);
    }
}

// ============ conv2: r8 structure (CIN=64, fused norm on staging) ============
template<int CIN, int NORM>
__global__ __launch_bounds__(256, 2) void conv_mfma(
    const unsigned short* __restrict__ in_hwc,
    const float2* __restrict__ stats_in,
    const unsigned short* __restrict__ wt,       // [ICC][2304 units] swizzled
    const float* __restrict__ bias,
    unsigned short* __restrict__ out_hwc,
    float2* __restrict__ partials)               // [B*400][64]
{
    constexpr int ICC = CIN / 32;

    __shared__ __align__(16) unsigned short sA[6 * 264 * 8];
    __shared__ __align__(16) unsigned short sW[2304 * 8];
    __shared__ float sRedS[256];
    __shared__ float sRedSS[256];
    __shared__ float2 sStats[64];

    const int tid = threadIdx.x;
    const int x0  = blockIdx.x * 64;
    const int y0  = blockIdx.y * 4;
    const int b   = blockIdx.z;
    const int w   = tid >> 6;
    const int l   = tid & 63;
    const int lm  = l & 15;
    const int g   = l >> 4;

    if (NORM) {
        if (tid < 64) sStats[tid] = stats_in[b * 64 + tid];
    }

    f32x4 acc[4][4];
#pragma unroll
    for (int fx = 0; fx < 4; ++fx)
#pragma unroll
        for (int fn = 0; fn < 4; ++fn)
            acc[fx][fn] = (f32x4){0.f, 0.f, 0.f, 0.f};

    for (int icc = 0; icc < ICC; ++icc) {
        __syncthreads();
        {
            const unsigned short* wsrc = wt + (size_t)icc * 2304 * 8;
            const int base = w * 576;
#pragma unroll
            for (int i = 0; i < 9; ++i)
                glds16(wsrc + (size_t)(base + i * 64 + l) * 8,
                       sW + (size_t)(base + i * 64) * 8);
        }
        if (NORM == 0) {
            for (int r = w; r < 6; r += 4) {
                int gy = y0 + r - 1;
                unsigned short* ldsrow = sA + r * 2112;
                if ((unsigned)gy < HH) {
                    const unsigned short* rowbase =
                        in_hwc + ((size_t)(b * HH + gy) * WW) * CIN + icc * 32;
#pragma unroll
                    for (int i = 0; i < 4; ++i) {
                        int u  = 4 + i * 64 + l;
                        int x  = u >> 2;
                        int cs = (u & 3) ^ ((x >> 1) & 3);
                        glds16(rowbase + (size_t)(x0 + x - 1) * CIN + cs * 8,
                               ldsrow + (size_t)(4 + i * 64) * 8);
                    }
                } else {
                    for (int u2 = l; u2 < 264; u2 += 64)
                        *(bf16x8*)(ldsrow + u2 * 8) = (bf16x8){0,0,0,0,0,0,0,0};
                }
            }
            if (tid < 48) {
                int icq = tid & 3, side = (tid >> 2) & 1, r = tid >> 3;
                int xs = side ? 65 : 0;
                int gy = y0 + r - 1, gx = x0 + xs - 1;
                bf16x8 v = (bf16x8){0,0,0,0,0,0,0,0};
                if ((unsigned)gy < HH && (unsigned)gx < WW)
                    v = *(const bf16x8*)&in_hwc[(((size_t)(b * HH + gy) * WW) + gx) * CIN + icc * 32 + icq * 8];
                *(bf16x8*)&sA[(r * 264 + xs * 4 + icq) * 8] = v;
            }
        } else {
#pragma unroll
            for (int k = 0; k < 7; ++k) {
                int e = tid + k * 256;
                if (e < 1584) {
                    int r = e / 264, rem = e - r * 264;
                    int x = rem >> 2, icq = rem & 3;
                    int gy = y0 + r - 1, gx = x0 + x - 1;
                    bf16x8 v = (bf16x8){0,0,0,0,0,0,0,0};
                    if ((unsigned)gy < HH && (unsigned)gx < WW)
                        v = *(const bf16x8*)&in_hwc[(((size_t)(b * HH + gy) * WW) + gx) * CIN + icc * 32 + icq * 8];
                    unsigned short res[8];
#pragma unroll
                    for (int j = 0; j < 8; ++j) {
                        float2 ms = sStats[icc * 32 + icq * 8 + j];
                        res[j] = f2bf(fmaxf((bf2f(((unsigned short*)&v)[j]) - ms.x) * ms.y, 0.f));
                    }
                    *(bf16x8*)&sA[(r * 264 + x * 4 + (icq ^ ((x >> 1) & 3))) * 8] = *(bf16x8*)res;
                }
            }
        }
        __syncthreads();

#pragma unroll
        for (int kk = 0; kk < 9; ++kk) {
            const int ky = kk / 3, kx = kk - ky * 3;
            bf16x8 af[4], bfr[4];
#pragma unroll
            for (int fx = 0; fx < 4; ++fx) {
                int xl = fx * 16 + lm + kx;
                int u  = (xl * 4 + g) ^ ((xl >> 1) & 3);
                af[fx] = *(const bf16x8*)&sA[((w + ky) * 264 + u) * 8];
            }
#pragma unroll
            for (int fn = 0; fn < 4; ++fn) {
                int ocr = fn * 16 + lm;
                int p   = (kk * 64 + ocr) * 4 + (g ^ ((ocr >> 1) & 3));
                bfr[fn] = *(const bf16x8*)&sW[p * 8];
            }
#pragma unroll
            for (int fn = 0; fn < 4; ++fn)
#pragma unroll
                for (int fx = 0; fx < 4; ++fx)
                    acc[fx][fn] = __builtin_amdgcn_mfma_f32_16x16x32_bf16(
                        bfr[fn], af[fx], acc[fx][fn], 0, 0, 0);
        }
    }

    const int row = y0 + w;
#pragma unroll
    for (int fo = 0; fo < 4; ++fo) {
        float4 b4 = *(const float4*)&bias[fo * 16 + g * 4];
        float bbv[4] = {b4.x, b4.y, b4.z, b4.w};
        float sj[4] = {0,0,0,0}, qj[4] = {0,0,0,0};
#pragma unroll
        for (int fp = 0; fp < 4; ++fp) {
            unsigned short pk[4];
#pragma unroll
            for (int j = 0; j < 4; ++j) {
                float v = acc[fp][fo][j] + bbv[j];
                sj[j] += v; qj[j] += v * v;
                pk[j] = f2bf(v);
            }
            *(short4*)&out_hwc[(((size_t)b * HH + row) * WW + x0 + fp * 16 + lm) * 64 + fo * 16 + g * 4] =
                *(short4*)pk;
        }
#pragma unroll
        for (int m = 1; m <= 8; m <<= 1)
#pragma unroll
            for (int j = 0; j < 4; ++j) {
                sj[j] += __shfl_xor(sj[j], m);
                qj[j] += __shfl_xor(qj[j], m);
            }
        if (lm == 0) {
#pragma unroll
            for (int j = 0; j < 4; ++j) {
                sRedS [w * 64 + fo * 16 + g * 4 + j] = sj[j];
                sRedSS[w * 64 + fo * 16 + g * 4 + j] = qj[j];
            }
        }
    }
    __syncthreads();
    if (tid < 64) {
        float S = 0.f, SS = 0.f;
#pragma unroll
        for (int q = 0; q < 4; ++q) { S += sRedS[q * 64 + tid]; SS += sRedSS[q * 64 + tid]; }
        partials[((size_t)b * 400 + blockIdx.y * 5 + blockIdx.x) * 64 + tid] = make_float2(S, SS);
    }
}

// ---------------- partials -> (mean, rstd) ----------------
__global__ __launch_bounds__(256) void reduce_stats(const float2* __restrict__ partials,
                                                    float2* __restrict__ stats, int count)
{
    const int b  = blockIdx.x;
    const int oc = threadIdx.x & 63;
    const int q  = threadIdx.x >> 6;
    float s = 0.f, ss = 0.f;
    for (int i = q; i < count; i += 4) {
        float2 p = partials[((size_t)b * count + i) * 64 + oc];
        s += p.x; ss += p.y;
    }
    __shared__ float2 red[4][64];
    red[q][oc] = make_float2(s, ss);
    __syncthreads();
    if (threadIdx.x < 64) {
        float S = 0.f, SS = 0.f;
#pragma unroll
        for (int k = 0; k < 4; ++k) { S += red[k][threadIdx.x].x; SS += red[k][threadIdx.x].y; }
        const float n = (float)(HH * WW);
        float mean = S / n;
        float var  = fmaxf(SS / n - mean * mean, 0.f);
        stats[b * 64 + threadIdx.x] = make_float2(mean, rsqrtf(var + EPS));
    }
}

// ------- final: read h2 NHWC bf16, norm+relu, register-transpose, NCHW fp32 -------
__global__ __launch_bounds__(256) void finalize_t(const unsigned short* __restrict__ h2,
                                                  const float2* __restrict__ stats,
                                                  float* __restrict__ out)
{
    __shared__ float2 sSt[64];
    const int tid = threadIdx.x;
    const int b   = blockIdx.z;
    if (tid < 64) sSt[tid] = stats[b * 64 + tid];
    __syncthreads();
    const int r   = tid >> 6;
    const int px  = tid & 63;
    const int row = blockIdx.y * 4 + r;
    const int x   = blockIdx.x * 64 + px;
    const unsigned short* src = h2 + ((size_t)(b * HH + row) * WW + x) * 64;
    bf16x8 v[8];
#pragma unroll
    for (int cq = 0; cq < 8; ++cq) v[cq] = *(const bf16x8*)(src + cq * 8);
#pragma unroll
    for (int cq = 0; cq < 8; ++cq)
#pragma unroll
        for (int j = 0; j < 8; ++j) {
            int c = cq * 8 + j;
            float2 ms = sSt[c];
            float f = fmaxf((bf2f(((unsigned short*)&v[cq])[j]) - ms.x) * ms.y, 0.f);
            out[((size_t)(b * 64 + c) * HH + row) * WW + x] = f;
        }
}

extern "C" void kernel_launch(void* const* d_in, const int* in_sizes, int n_in,
                              void* d_out, int out_size, void* d_ws, size_t ws_size,
                              hipStream_t stream)
{
    const float* x  = (const float*)d_in[0];
    const float* w1 = (const float*)d_in[1];
    const float* b1 = (const float*)d_in[2];
    const float* w2 = (const float*)d_in[3];
    const float* b2 = (const float*)d_in[4];
    float* out = (float*)d_out;

    char* ws = (char*)d_ws;
    unsigned short* h    = (unsigned short*)ws;                         // 105 MB NHWC bf16
    float2* partials     = (float2*)(ws + 104857600);                   // 1.6 MB
    float2* stats1       = (float2*)(ws + 104857600 + 1638400);
    float2* stats2       = (float2*)(ws + 104857600 + 1638400 + 4096);
    unsigned short* reg2 = (unsigned short*)(ws + 104857600 + 1638400 + 8192);
    unsigned short* x_hwc = reg2;   // 52 MB, dead after conv1
    unsigned short* h2    = reg2;   // 105 MB, conv2 output

    unsigned short* wt2 = (unsigned short*)((char*)d_out + 209715200 - 73728);
    unsigned short* wt1 = (unsigned short*)((char*)d_out + 209715200 - 73728 - 36864);

    wprep_swz<<<18, 256, 0, stream>>>(w1, w2, wt1, wt2);
    prep_hwc<<<dim3(5, HH, BB), 256, 0, stream>>>(x, x_hwc);

    // conv1: ring supertile, 800 blocks
    conv1_ring<<<dim3(5, 20, BB), 256, 0, stream>>>(x_hwc, wt1, b1, h, partials);
    reduce_stats<<<BB, 256, 0, stream>>>(partials, stats1, 100);
    // conv2: r8 structure, 3200 blocks
    conv_mfma<64, 1><<<dim3(5, 80, BB), 256, 0, stream>>>(h, stats1, wt2, b2, h2, partials);
    reduce_stats<<<BB, 256, 0, stream>>>(partials, stats2, 400);
    finalize_t<<<dim3(5, 80, BB), 256, 0, stream>>>(h2, stats2, out);
}